// Round 1
// 255.770 us; speedup vs baseline: 1.0695x; 1.0695x over previous
//
#include <hip/hip_runtime.h>
#include <hip/hip_fp16.h>
#include <math.h>

// GCN: out = softmax( S·relu((S·h)W1 + b1) · W2 + b2 ),  S = in-edge sum + self-loop.
// Round 11: both gathers restructured to PREDICATED FULL-COVERAGE batching.
// Old code had a serial scalar tail loop (1-3 dependent L3 round-trips per node)
// that dominated the latency-bound gathers. New: clamp indices + weight-masked FMA
// so one deep batch covers the whole node (gather1: 4x16 lanes, 8B loads, batch-8
// -> d<=32 in one round; gather2: 3x20 lanes, batch-8 -> d<=24 in one round).

constexpr int N = 100000;
constexpr int E = 1200000;
constexpr int D = 64;    // input dim
constexpr int H = 128;   // hidden
constexpr int C = 40;    // classes
constexpr int NBUCK2 = 98;                      // buckets of 1024 dst nodes
constexpr int EBLK   = 2048;                    // edges per histo/append block
constexpr int NHB    = (E + EBLK - 1) / EBLK;   // 586 edge blocks

// ---- h (fp32) -> HH (fp16), row = 64 halves = 128 B ----
__global__ __launch_bounds__(256) void convert_h(const float2* __restrict__ hf,
                                                 __half2* __restrict__ HH) {
    int i = (blockIdx.x * 256 + threadIdx.x) * 4;   // N*32 half2, exact
#pragma unroll
    for (int k = 0; k < 4; ++k) {
        float2 p = hf[i + k];
        HH[i + k] = __floats2half2_rn(p.x, p.y);
    }
}

// ---- per-block LDS bucket histogram (98 buckets), dense partial dump ----
__global__ __launch_bounds__(256) void histo_b(const int2* __restrict__ edges,
                                               int* __restrict__ partial) {
    __shared__ int cnt[NBUCK2];
    if (threadIdx.x < NBUCK2) cnt[threadIdx.x] = 0;
    __syncthreads();
    int base = blockIdx.x * EBLK + threadIdx.x * 8;
#pragma unroll
    for (int i = 0; i < 8; ++i) {
        int e = base + i;
        if (e < E) atomicAdd(&cnt[edges[e].y >> 10], 1);
    }
    __syncthreads();
    if (threadIdx.x < NBUCK2)
        partial[blockIdx.x * NBUCK2 + threadIdx.x] = cnt[threadIdx.x];
}

// ---- per-bucket column scan of partial: obase[b][blk], btot[b] ----
__global__ __launch_bounds__(1024) void scan_pb(const int* __restrict__ partial,
                                                int* __restrict__ obase,
                                                int* __restrict__ btot) {
    __shared__ int s[1024];
    int b = blockIdx.x, t = threadIdx.x;
    int v = (t < NHB) ? partial[t * NBUCK2 + b] : 0;
    s[t] = v;
    __syncthreads();
    for (int off = 1; off < 1024; off <<= 1) {
        int x = (t >= off) ? s[t - off] : 0;
        __syncthreads();
        s[t] += x;
        __syncthreads();
    }
    if (t < NHB) obase[b * NHB + t] = s[t] - v;   // exclusive within bucket
    if (t == 1023) btot[b] = s[1023];
}

// ---- exclusive scan of bucket totals -> bstart[0..NBUCK2] ----
__global__ __launch_bounds__(128) void scan_bt(const int* __restrict__ btot,
                                               int* __restrict__ bstart) {
    __shared__ int s[128];
    int t = threadIdx.x;
    int v = (t < NBUCK2) ? btot[t] : 0;
    s[t] = v;
    __syncthreads();
    for (int off = 1; off < 128; off <<= 1) {
        int x = (t >= off) ? s[t - off] : 0;
        __syncthreads();
        s[t] += x;
        __syncthreads();
    }
    if (t < NBUCK2) bstart[t] = s[t] - v;
    if (t == NBUCK2 - 1) bstart[NBUCK2] = s[t];   // = E
}

// ---- append: deterministic positions, LDS cursors seeded from scanned bases ----
__global__ __launch_bounds__(256) void append_b(const int2* __restrict__ edges,
                                                const int* __restrict__ bstart,
                                                const int* __restrict__ obase,
                                                int* __restrict__ staging) {
    __shared__ int cur[NBUCK2];
    int blk = blockIdx.x;
    if (threadIdx.x < NBUCK2)
        cur[threadIdx.x] = bstart[threadIdx.x] + obase[threadIdx.x * NHB + blk];
    __syncthreads();
    int base = blk * EBLK + threadIdx.x * 8;
#pragma unroll
    for (int i = 0; i < 8; ++i) {
        int e = base + i;
        if (e < E) {
            int2 ed = edges[e];
            int b = ed.y >> 10;
            int p = atomicAdd(&cur[b], 1);               // LDS atomic
            staging[p] = (ed.x << 10) | (ed.y & 1023);   // src:17b | dst_local:10b
        }
    }
}

// ---- per-bucket: LDS count + scan -> deg/row_start, scatter csr in window ----
__global__ __launch_bounds__(1024) void fill_b(const int* __restrict__ staging,
                                               const int* __restrict__ bstart,
                                               int* __restrict__ deg,
                                               int* __restrict__ row_start,
                                               int* __restrict__ csr) {
    __shared__ int cnt[1024], s[1024], cur[1024];
    int b = blockIdx.x, t = threadIdx.x;
    cnt[t] = 0;
    __syncthreads();
    int lo = bstart[b], hi = bstart[b + 1];
    for (int i = lo + t; i < hi; i += 1024)
        atomicAdd(&cnt[staging[i] & 1023], 1);
    __syncthreads();
    int v = cnt[t];
    s[t] = v;
    __syncthreads();
    for (int off = 1; off < 1024; off <<= 1) {
        int x = (t >= off) ? s[t - off] : 0;
        __syncthreads();
        s[t] += x;
        __syncthreads();
    }
    int ex = s[t] - v;
    cur[t] = ex;
    int node = (b << 10) + t;
    if (node < N) { deg[node] = v; row_start[node] = lo + ex; }
    __syncthreads();
    for (int i = lo + t; i < hi; i += 1024) {
        int w = staging[i];
        int p = atomicAdd(&cur[w & 1023], 1);
        csr[lo + p] = w >> 10;
    }
}

// ---- layer-1 gather (fp16 rows): 4 groups x 16 lanes, 8B loads, batch-8 predicated.
//      One batch covers all edges of a node for d <= 32 (P(exceed) ~ 1e-6). ----
__global__ __launch_bounds__(256) void gather1(const __half2* __restrict__ HH,
                                               const int* __restrict__ csr,
                                               const int* __restrict__ row_start,
                                               const int* __restrict__ deg,
                                               float2* __restrict__ agg) {
    int node = blockIdx.x * 4 + (threadIdx.x >> 6);
    int lane = threadIdx.x & 63;
    int g  = lane >> 4;        // 0..3 : edges j == g (mod 4)
    int fl = lane & 15;        // float2 chunk: halves 4*fl .. 4*fl+3
    const float2* H4 = (const float2*)HH;     // row = 16 float2 (= 32 half2)
    int rs = row_start[node], d = deg[node];
    float a0 = 0.f, a1 = 0.f, a2 = 0.f, a3 = 0.f;
    if (g == 0) {              // self-loop
        float2 raw = H4[node * 16 + fl];
        const __half2* hp = (const __half2*)&raw;
        float2 v0 = __half22float2(hp[0]), v1 = __half22float2(hp[1]);
        a0 = v0.x; a1 = v0.y; a2 = v1.x; a3 = v1.y;
    }
    int cl = (d > 0) ? d - 1 : 0;
    for (int j0 = g; j0 < d; j0 += 32) {       // 8 rows in flight per group
        int k[8]; float w[8];
#pragma unroll
        for (int t = 0; t < 8; ++t) {
            int jj = j0 + 4 * t;
            bool ok = jj < d;
            w[t] = ok ? 1.f : 0.f;
            k[t] = csr[rs + (ok ? jj : cl)];
        }
#pragma unroll
        for (int t = 0; t < 8; ++t) {
            float2 raw = H4[k[t] * 16 + fl];
            const __half2* hp = (const __half2*)&raw;
            float2 v0 = __half22float2(hp[0]), v1 = __half22float2(hp[1]);
            a0 = fmaf(w[t], v0.x, a0); a1 = fmaf(w[t], v0.y, a1);
            a2 = fmaf(w[t], v1.x, a2); a3 = fmaf(w[t], v1.y, a3);
        }
    }
    // combine the 4 edge-subset groups (g differs, fl matches across xor 16/32)
    a0 += __shfl_xor(a0, 16); a0 += __shfl_xor(a0, 32);
    a1 += __shfl_xor(a1, 16); a1 += __shfl_xor(a1, 32);
    a2 += __shfl_xor(a2, 16); a2 += __shfl_xor(a2, 32);
    a3 += __shfl_xor(a3, 16); a3 += __shfl_xor(a3, 32);
    if (lane < 16)
        ((float4*)agg)[node * 16 + fl] = make_float4(a0, a1, a2, a3);
}

// ---- XH = fp16(relu(agg @ W1 + b1)), tiled ----
__global__ __launch_bounds__(256) void gemm1_relu(const float* __restrict__ A,
                                                  const float* __restrict__ W1,
                                                  const float* __restrict__ b1,
                                                  __half* __restrict__ XH) {
    __shared__ float w_s[D * H];      // 32 KB
    __shared__ float a_s[16 * D];     // 4 KB
    int row0 = blockIdx.x * 16;
    {
        const float4* src = (const float4*)W1;
        float4* dst = (float4*)w_s;
#pragma unroll
        for (int i = 0; i < 8; ++i)
            dst[threadIdx.x + i * 256] = src[threadIdx.x + i * 256];
    }
    {
        int r = threadIdx.x >> 4;
        int q = threadIdx.x & 15;
        float4 v = *(const float4*)&A[(row0 + r) * D + q * 4];
        *(float4*)&a_s[r * D + q * 4] = v;
    }
    __syncthreads();

    int tr   = threadIdx.x >> 6;
    int lane = threadIdx.x & 63;
    float acc[4][2] = {};
#pragma unroll
    for (int k = 0; k < D; ++k) {
        float b0 = w_s[k * H + lane];
        float b1v = w_s[k * H + lane + 64];
#pragma unroll
        for (int i = 0; i < 4; ++i) {
            float a = a_s[(tr + 4 * i) * D + k];
            acc[i][0] = fmaf(a, b0, acc[i][0]);
            acc[i][1] = fmaf(a, b1v, acc[i][1]);
        }
    }
    float bias0 = b1[lane], bias1 = b1[lane + 64];
#pragma unroll
    for (int i = 0; i < 4; ++i) {
        int row = row0 + tr + 4 * i;
        XH[row * H + lane]      = __float2half_rn(fmaxf(acc[i][0] + bias0, 0.f));
        XH[row * H + lane + 64] = __float2half_rn(fmaxf(acc[i][1] + bias1, 0.f));
    }
}

// ---- ZH = fp16(XH @ W2), row stride 64 halves, cols 40..63 zero-filled ----
constexpr int XS = 132;
__global__ __launch_bounds__(256) void gemm2(const __half* __restrict__ XH,
                                             const float* __restrict__ W2,
                                             __half* __restrict__ ZH) {
    __shared__ float w_s[H * C];        // 20 KB
    __shared__ float x_s[64 * XS];      // 33.8 KB
    int row0 = blockIdx.x * 64;
    {
        const float4* src = (const float4*)W2;
        float4* dst = (float4*)w_s;
#pragma unroll
        for (int i = 0; i < 5; ++i)
            dst[threadIdx.x + i * 256] = src[threadIdx.x + i * 256];
    }
    {   // stage XH (fp16) -> x_s (fp32): 64 rows x 16 chunks of 8 halves
#pragma unroll
        for (int i = 0; i < 4; ++i) {
            int idx = threadIdx.x + i * 256;   // 1024 chunks
            int r = idx >> 4;
            int q = idx & 15;
            int grow = row0 + r;
            if (grow >= N) grow = N - 1;
            float4 raw = *(const float4*)&XH[grow * H + q * 8];
            __half2* hp = (__half2*)&raw;
            float2 f0 = __half22float2(hp[0]), f1 = __half22float2(hp[1]);
            float2 f2 = __half22float2(hp[2]), f3 = __half22float2(hp[3]);
            float* dst = &x_s[r * XS + q * 8];
            dst[0] = f0.x; dst[1] = f0.y; dst[2] = f1.x; dst[3] = f1.y;
            dst[4] = f2.x; dst[5] = f2.y; dst[6] = f3.x; dst[7] = f3.y;
        }
    }
    __syncthreads();

    int tc   = threadIdx.x & 7;         // cols tc*5 .. tc*5+4
    int trow = threadIdx.x >> 3;        // rows trow*2, trow*2+1
    float acc[2][5] = {};
#pragma unroll 4
    for (int k = 0; k < H; ++k) {
        float b[5];
#pragma unroll
        for (int j = 0; j < 5; ++j) b[j] = w_s[k * C + tc * 5 + j];
        float a0 = x_s[(trow * 2) * XS + k];
        float a1 = x_s[(trow * 2 + 1) * XS + k];
#pragma unroll
        for (int j = 0; j < 5; ++j) {
            acc[0][j] = fmaf(a0, b[j], acc[0][j]);
            acc[1][j] = fmaf(a1, b[j], acc[1][j]);
        }
    }
#pragma unroll
    for (int i = 0; i < 2; ++i) {
        int row = row0 + trow * 2 + i;
        if (row < N) {
#pragma unroll
            for (int j = 0; j < 5; ++j)
                ZH[row * 64 + tc * 5 + j] = __float2half_rn(acc[i][j]);
#pragma unroll
            for (int j = 0; j < 3; ++j)          // pad cols 40..63
                ZH[row * 64 + 40 + tc * 3 + j] = __half(0.f);
        }
    }
}

// ---- out[node] = softmax(Z[node] + sum Z[src] + b2); 3x20 lanes, batch-8 predicated ----
__global__ __launch_bounds__(256) void gather2_softmax(const __half2* __restrict__ ZH,
                                                       const int* __restrict__ csr,
                                                       const int* __restrict__ row_start,
                                                       const int* __restrict__ deg,
                                                       const float2* __restrict__ b2,
                                                       float2* __restrict__ out) {
    int node = blockIdx.x * 4 + (threadIdx.x >> 6);
    int lane = threadIdx.x & 63;
    int g  = (lane >= 40) ? 2 : (lane >= 20 ? 1 : 0);
    if (lane >= 60) g = 3;                               // inactive
    int fl = lane - g * 20;                              // half2 index
    bool active = (g < 3);
    int rs = row_start[node], d = deg[node];
    float ax = 0.f, ay = 0.f;
    if (g == 0) {                                        // self-loop
        float2 v = __half22float2(ZH[node * 32 + fl]);
        ax = v.x; ay = v.y;
    }
    if (active) {
        int cl = (d > 0) ? d - 1 : 0;
        for (int j0 = g; j0 < d; j0 += 24) {             // 8 rows in flight per group
            int k[8]; float w[8];
#pragma unroll
            for (int t = 0; t < 8; ++t) {
                int jj = j0 + 3 * t;
                bool ok = jj < d;
                w[t] = ok ? 1.f : 0.f;
                k[t] = csr[rs + (ok ? jj : cl)];
            }
#pragma unroll
            for (int t = 0; t < 8; ++t) {
                float2 v = __half22float2(ZH[k[t] * 32 + fl]);
                ax = fmaf(w[t], v.x, ax);
                ay = fmaf(w[t], v.y, ay);
            }
        }
    }
    ax += __shfl(ax, (lane + 20) & 63) + __shfl(ax, (lane + 40) & 63);
    ay += __shfl(ay, (lane + 20) & 63) + __shfl(ay, (lane + 40) & 63);
    float vx = -INFINITY, vy = -INFINITY;
    if (lane < 20) {
        float2 bbv = b2[lane];
        vx = ax + bbv.x;
        vy = ay + bbv.y;
    }
    float m = fmaxf(vx, vy);
#pragma unroll
    for (int off = 16; off; off >>= 1) m = fmaxf(m, __shfl_xor(m, off));
    float ex = (lane < 20) ? __expf(vx - m) : 0.f;
    float ey = (lane < 20) ? __expf(vy - m) : 0.f;
    float ssum = ex + ey;
#pragma unroll
    for (int off = 16; off; off >>= 1) ssum += __shfl_xor(ssum, off);
    if (lane < 20) {
        float inv = 1.f / ssum;
        out[node * 20 + lane] = make_float2(ex * inv, ey * inv);
    }
}

extern "C" void kernel_launch(void* const* d_in, const int* in_sizes, int n_in,
                              void* d_out, int out_size, void* d_ws, size_t ws_size,
                              hipStream_t stream) {
    const float* h   = (const float*)d_in[0];   // N*D
    const int*   adj = (const int*)  d_in[1];   // E*2
    const float* W1  = (const float*)d_in[2];   // D*H
    const float* b1  = (const float*)d_in[3];   // H
    const float* W2  = (const float*)d_in[4];   // H*C
    const float* b2  = (const float*)d_in[5];   // C
    float* out = (float*)d_out;                 // N*C fp32

    // workspace (~87.7 MB), NO aliasing:
    //   agg1 fp32 N*64 | HH fp16 N*64 | XH fp16 N*128 | ZH fp16 N*64 | ints
    float*  agg1 = (float*)d_ws;                        // N*64 fp32
    __half* HH   = (__half*)(agg1 + (size_t)N * 64);    // N*64 fp16
    __half* XH   = HH + (size_t)N * 64;                 // N*128 fp16
    __half* ZH   = XH + (size_t)N * H;                  // N*64 fp16
    int* partial   = (int*)(ZH + (size_t)N * 64);       // NHB*NBUCK2
    int* obase     = partial + NHB * NBUCK2;            // NBUCK2*NHB
    int* btot      = obase + NBUCK2 * NHB;              // 128
    int* bstart    = btot + 128;                        // NBUCK2+1 (pad 128)
    int* staging   = bstart + 128;                      // E
    int* csr       = staging + E;                       // E
    int* deg       = csr + E;                           // N
    int* row_start = deg + N;                           // N

    convert_h<<<N * 32 / (256 * 4), 256, 0, stream>>>((const float2*)h, (__half2*)HH);
    histo_b  <<<NHB, 256, 0, stream>>>((const int2*)adj, partial);
    scan_pb  <<<NBUCK2, 1024, 0, stream>>>(partial, obase, btot);
    scan_bt  <<<1, 128, 0, stream>>>(btot, bstart);
    append_b <<<NHB, 256, 0, stream>>>((const int2*)adj, bstart, obase, staging);
    fill_b   <<<NBUCK2, 1024, 0, stream>>>(staging, bstart, deg, row_start, csr);

    gather1        <<<N / 4, 256, 0, stream>>>((const __half2*)HH, csr, row_start, deg,
                                               (float2*)agg1);
    gemm1_relu     <<<N / 16, 256, 0, stream>>>(agg1, W1, b1, XH);
    gemm2          <<<(N + 63) / 64, 256, 0, stream>>>(XH, W2, ZH);
    gather2_softmax<<<N / 4, 256, 0, stream>>>((const __half2*)ZH, csr, row_start, deg,
                                               (const float2*)b2, (float2*)out);
}

// Round 2
// 252.069 us; speedup vs baseline: 1.0852x; 1.0147x over previous
//
#include <hip/hip_runtime.h>
#include <hip/hip_fp16.h>
#include <math.h>

// GCN: out = softmax( S·relu((S·h)W1 + b1) · W2 + b2 ),  S = in-edge sum + self-loop.
// Round 12: two-tier wave-uniform batching in both gathers. Round-11's always-on
// deep batches wasted ~2.5x predicated slots (mean deg 12-13 vs 32/24 slots).
// Now: round 1 sized to cover d<=16 (g1) / d<=15 (g2); round 2 only for the
// ~10-16% of waves exceeding it (d is wave-uniform -> no divergence); scalar
// safety tail beyond 32/30 (P ~ 1e-7). Also: (row_start,deg) packed into int2.

constexpr int N = 100000;
constexpr int E = 1200000;
constexpr int D = 64;    // input dim
constexpr int H = 128;   // hidden
constexpr int C = 40;    // classes
constexpr int NBUCK2 = 98;                      // buckets of 1024 dst nodes
constexpr int EBLK   = 2048;                    // edges per histo/append block
constexpr int NHB    = (E + EBLK - 1) / EBLK;   // 586 edge blocks

// ---- h (fp32) -> HH (fp16), row = 64 halves = 128 B ----
__global__ __launch_bounds__(256) void convert_h(const float2* __restrict__ hf,
                                                 __half2* __restrict__ HH) {
    int i = (blockIdx.x * 256 + threadIdx.x) * 4;   // N*32 half2, exact
#pragma unroll
    for (int k = 0; k < 4; ++k) {
        float2 p = hf[i + k];
        HH[i + k] = __floats2half2_rn(p.x, p.y);
    }
}

// ---- per-block LDS bucket histogram (98 buckets), dense partial dump ----
__global__ __launch_bounds__(256) void histo_b(const int2* __restrict__ edges,
                                               int* __restrict__ partial) {
    __shared__ int cnt[NBUCK2];
    if (threadIdx.x < NBUCK2) cnt[threadIdx.x] = 0;
    __syncthreads();
    int base = blockIdx.x * EBLK + threadIdx.x * 8;
#pragma unroll
    for (int i = 0; i < 8; ++i) {
        int e = base + i;
        if (e < E) atomicAdd(&cnt[edges[e].y >> 10], 1);
    }
    __syncthreads();
    if (threadIdx.x < NBUCK2)
        partial[blockIdx.x * NBUCK2 + threadIdx.x] = cnt[threadIdx.x];
}

// ---- per-bucket column scan of partial: obase[b][blk], btot[b] ----
__global__ __launch_bounds__(1024) void scan_pb(const int* __restrict__ partial,
                                                int* __restrict__ obase,
                                                int* __restrict__ btot) {
    __shared__ int s[1024];
    int b = blockIdx.x, t = threadIdx.x;
    int v = (t < NHB) ? partial[t * NBUCK2 + b] : 0;
    s[t] = v;
    __syncthreads();
    for (int off = 1; off < 1024; off <<= 1) {
        int x = (t >= off) ? s[t - off] : 0;
        __syncthreads();
        s[t] += x;
        __syncthreads();
    }
    if (t < NHB) obase[b * NHB + t] = s[t] - v;   // exclusive within bucket
    if (t == 1023) btot[b] = s[1023];
}

// ---- exclusive scan of bucket totals -> bstart[0..NBUCK2] ----
__global__ __launch_bounds__(128) void scan_bt(const int* __restrict__ btot,
                                               int* __restrict__ bstart) {
    __shared__ int s[128];
    int t = threadIdx.x;
    int v = (t < NBUCK2) ? btot[t] : 0;
    s[t] = v;
    __syncthreads();
    for (int off = 1; off < 128; off <<= 1) {
        int x = (t >= off) ? s[t - off] : 0;
        __syncthreads();
        s[t] += x;
        __syncthreads();
    }
    if (t < NBUCK2) bstart[t] = s[t] - v;
    if (t == NBUCK2 - 1) bstart[NBUCK2] = s[t];   // = E
}

// ---- append: deterministic positions, LDS cursors seeded from scanned bases ----
__global__ __launch_bounds__(256) void append_b(const int2* __restrict__ edges,
                                                const int* __restrict__ bstart,
                                                const int* __restrict__ obase,
                                                int* __restrict__ staging) {
    __shared__ int cur[NBUCK2];
    int blk = blockIdx.x;
    if (threadIdx.x < NBUCK2)
        cur[threadIdx.x] = bstart[threadIdx.x] + obase[threadIdx.x * NHB + blk];
    __syncthreads();
    int base = blk * EBLK + threadIdx.x * 8;
#pragma unroll
    for (int i = 0; i < 8; ++i) {
        int e = base + i;
        if (e < E) {
            int2 ed = edges[e];
            int b = ed.y >> 10;
            int p = atomicAdd(&cur[b], 1);               // LDS atomic
            staging[p] = (ed.x << 10) | (ed.y & 1023);   // src:17b | dst_local:10b
        }
    }
}

// ---- per-bucket: LDS count + scan -> rd(row_start,deg), scatter csr in window ----
__global__ __launch_bounds__(1024) void fill_b(const int* __restrict__ staging,
                                               const int* __restrict__ bstart,
                                               int2* __restrict__ rd,
                                               int* __restrict__ csr) {
    __shared__ int cnt[1024], s[1024], cur[1024];
    int b = blockIdx.x, t = threadIdx.x;
    cnt[t] = 0;
    __syncthreads();
    int lo = bstart[b], hi = bstart[b + 1];
    for (int i = lo + t; i < hi; i += 1024)
        atomicAdd(&cnt[staging[i] & 1023], 1);
    __syncthreads();
    int v = cnt[t];
    s[t] = v;
    __syncthreads();
    for (int off = 1; off < 1024; off <<= 1) {
        int x = (t >= off) ? s[t - off] : 0;
        __syncthreads();
        s[t] += x;
        __syncthreads();
    }
    int ex = s[t] - v;
    cur[t] = ex;
    int node = (b << 10) + t;
    if (node < N) rd[node] = make_int2(lo + ex, v);
    __syncthreads();
    for (int i = lo + t; i < hi; i += 1024) {
        int w = staging[i];
        int p = atomicAdd(&cur[w & 1023], 1);
        csr[lo + p] = w >> 10;
    }
}

// ---- layer-1 gather (fp16 rows): 4 groups x 16 lanes, 8B loads, two-tier batch.
//      Round 1 covers d<=16 (always); round 2 covers d<=32 (10.5% of waves);
//      scalar tail beyond (P ~ 1e-7). d is wave-uniform -> branches uniform. ----
__global__ __launch_bounds__(256) void gather1(const __half2* __restrict__ HH,
                                               const int* __restrict__ csr,
                                               const int2* __restrict__ rd,
                                               float2* __restrict__ agg) {
    int node = blockIdx.x * 4 + (threadIdx.x >> 6);
    int lane = threadIdx.x & 63;
    int g  = lane >> 4;        // 0..3 : edges j == g (mod 4)
    int fl = lane & 15;        // float2 chunk: halves 4*fl .. 4*fl+3
    const float2* H4 = (const float2*)HH;     // row = 16 float2 (= 32 half2)
    int2 rdv = rd[node];
    int rs = rdv.x, d = rdv.y;
    float a0 = 0.f, a1 = 0.f, a2 = 0.f, a3 = 0.f;
    if (g == 0) {              // self-loop
        float2 raw = H4[node * 16 + fl];
        const __half2* hp = (const __half2*)&raw;
        float2 v0 = __half22float2(hp[0]), v1 = __half22float2(hp[1]);
        a0 = v0.x; a1 = v0.y; a2 = v1.x; a3 = v1.y;
    }
    if (d > 0) {
        int cl = d - 1;
        int k[4]; float w[4];
        // ---- round 1: 16 rows in flight wave-wide, covers j < 16 ----
#pragma unroll
        for (int t = 0; t < 4; ++t) {
            int jj = g + 4 * t;
            bool ok = jj < d;
            w[t] = ok ? 1.f : 0.f;
            k[t] = csr[rs + (ok ? jj : cl)];
        }
#pragma unroll
        for (int t = 0; t < 4; ++t) {
            float2 raw = H4[k[t] * 16 + fl];
            const __half2* hp = (const __half2*)&raw;
            float2 v0 = __half22float2(hp[0]), v1 = __half22float2(hp[1]);
            a0 = fmaf(w[t], v0.x, a0); a1 = fmaf(w[t], v0.y, a1);
            a2 = fmaf(w[t], v1.x, a2); a3 = fmaf(w[t], v1.y, a3);
        }
        if (d > 16) {
            // ---- round 2: covers 16 <= j < 32 (~10.5% of waves) ----
#pragma unroll
            for (int t = 0; t < 4; ++t) {
                int jj = 16 + g + 4 * t;
                bool ok = jj < d;
                w[t] = ok ? 1.f : 0.f;
                k[t] = csr[rs + (ok ? jj : cl)];
            }
#pragma unroll
            for (int t = 0; t < 4; ++t) {
                float2 raw = H4[k[t] * 16 + fl];
                const __half2* hp = (const __half2*)&raw;
                float2 v0 = __half22float2(hp[0]), v1 = __half22float2(hp[1]);
                a0 = fmaf(w[t], v0.x, a0); a1 = fmaf(w[t], v0.y, a1);
                a2 = fmaf(w[t], v1.x, a2); a3 = fmaf(w[t], v1.y, a3);
            }
            for (int j = 32 + g; j < d; j += 4) {   // safety tail, ~never
                float2 raw = H4[csr[rs + j] * 16 + fl];
                const __half2* hp = (const __half2*)&raw;
                float2 v0 = __half22float2(hp[0]), v1 = __half22float2(hp[1]);
                a0 += v0.x; a1 += v0.y; a2 += v1.x; a3 += v1.y;
            }
        }
    }
    // combine the 4 edge-subset groups (g differs, fl matches across xor 16/32)
    a0 += __shfl_xor(a0, 16); a0 += __shfl_xor(a0, 32);
    a1 += __shfl_xor(a1, 16); a1 += __shfl_xor(a1, 32);
    a2 += __shfl_xor(a2, 16); a2 += __shfl_xor(a2, 32);
    a3 += __shfl_xor(a3, 16); a3 += __shfl_xor(a3, 32);
    if (lane < 16)
        ((float4*)agg)[node * 16 + fl] = make_float4(a0, a1, a2, a3);
}

// ---- XH = fp16(relu(agg @ W1 + b1)), tiled ----
__global__ __launch_bounds__(256) void gemm1_relu(const float* __restrict__ A,
                                                  const float* __restrict__ W1,
                                                  const float* __restrict__ b1,
                                                  __half* __restrict__ XH) {
    __shared__ float w_s[D * H];      // 32 KB
    __shared__ float a_s[16 * D];     // 4 KB
    int row0 = blockIdx.x * 16;
    {
        const float4* src = (const float4*)W1;
        float4* dst = (float4*)w_s;
#pragma unroll
        for (int i = 0; i < 8; ++i)
            dst[threadIdx.x + i * 256] = src[threadIdx.x + i * 256];
    }
    {
        int r = threadIdx.x >> 4;
        int q = threadIdx.x & 15;
        float4 v = *(const float4*)&A[(row0 + r) * D + q * 4];
        *(float4*)&a_s[r * D + q * 4] = v;
    }
    __syncthreads();

    int tr   = threadIdx.x >> 6;
    int lane = threadIdx.x & 63;
    float acc[4][2] = {};
#pragma unroll
    for (int k = 0; k < D; ++k) {
        float b0 = w_s[k * H + lane];
        float b1v = w_s[k * H + lane + 64];
#pragma unroll
        for (int i = 0; i < 4; ++i) {
            float a = a_s[(tr + 4 * i) * D + k];
            acc[i][0] = fmaf(a, b0, acc[i][0]);
            acc[i][1] = fmaf(a, b1v, acc[i][1]);
        }
    }
    float bias0 = b1[lane], bias1 = b1[lane + 64];
#pragma unroll
    for (int i = 0; i < 4; ++i) {
        int row = row0 + tr + 4 * i;
        XH[row * H + lane]      = __float2half_rn(fmaxf(acc[i][0] + bias0, 0.f));
        XH[row * H + lane + 64] = __float2half_rn(fmaxf(acc[i][1] + bias1, 0.f));
    }
}

// ---- ZH = fp16(XH @ W2), row stride 64 halves, cols 40..63 zero-filled ----
constexpr int XS = 132;
__global__ __launch_bounds__(256) void gemm2(const __half* __restrict__ XH,
                                             const float* __restrict__ W2,
                                             __half* __restrict__ ZH) {
    __shared__ float w_s[H * C];        // 20 KB
    __shared__ float x_s[64 * XS];      // 33.8 KB
    int row0 = blockIdx.x * 64;
    {
        const float4* src = (const float4*)W2;
        float4* dst = (float4*)w_s;
#pragma unroll
        for (int i = 0; i < 5; ++i)
            dst[threadIdx.x + i * 256] = src[threadIdx.x + i * 256];
    }
    {   // stage XH (fp16) -> x_s (fp32): 64 rows x 16 chunks of 8 halves
#pragma unroll
        for (int i = 0; i < 4; ++i) {
            int idx = threadIdx.x + i * 256;   // 1024 chunks
            int r = idx >> 4;
            int q = idx & 15;
            int grow = row0 + r;
            if (grow >= N) grow = N - 1;
            float4 raw = *(const float4*)&XH[grow * H + q * 8];
            __half2* hp = (__half2*)&raw;
            float2 f0 = __half22float2(hp[0]), f1 = __half22float2(hp[1]);
            float2 f2 = __half22float2(hp[2]), f3 = __half22float2(hp[3]);
            float* dst = &x_s[r * XS + q * 8];
            dst[0] = f0.x; dst[1] = f0.y; dst[2] = f1.x; dst[3] = f1.y;
            dst[4] = f2.x; dst[5] = f2.y; dst[6] = f3.x; dst[7] = f3.y;
        }
    }
    __syncthreads();

    int tc   = threadIdx.x & 7;         // cols tc*5 .. tc*5+4
    int trow = threadIdx.x >> 3;        // rows trow*2, trow*2+1
    float acc[2][5] = {};
#pragma unroll 4
    for (int k = 0; k < H; ++k) {
        float b[5];
#pragma unroll
        for (int j = 0; j < 5; ++j) b[j] = w_s[k * C + tc * 5 + j];
        float a0 = x_s[(trow * 2) * XS + k];
        float a1 = x_s[(trow * 2 + 1) * XS + k];
#pragma unroll
        for (int j = 0; j < 5; ++j) {
            acc[0][j] = fmaf(a0, b[j], acc[0][j]);
            acc[1][j] = fmaf(a1, b[j], acc[1][j]);
        }
    }
#pragma unroll
    for (int i = 0; i < 2; ++i) {
        int row = row0 + trow * 2 + i;
        if (row < N) {
#pragma unroll
            for (int j = 0; j < 5; ++j)
                ZH[row * 64 + tc * 5 + j] = __float2half_rn(acc[i][j]);
#pragma unroll
            for (int j = 0; j < 3; ++j)          // pad cols 40..63
                ZH[row * 64 + 40 + tc * 3 + j] = __half(0.f);
        }
    }
}

// ---- out[node] = softmax(Z[node] + sum Z[src] + b2); 3x20 lanes, two-tier batch ----
__global__ __launch_bounds__(256) void gather2_softmax(const __half2* __restrict__ ZH,
                                                       const int* __restrict__ csr,
                                                       const int2* __restrict__ rd,
                                                       const float2* __restrict__ b2,
                                                       float2* __restrict__ out) {
    int node = blockIdx.x * 4 + (threadIdx.x >> 6);
    int lane = threadIdx.x & 63;
    int g  = (lane >= 40) ? 2 : (lane >= 20 ? 1 : 0);
    if (lane >= 60) g = 3;                               // inactive
    int fl = lane - g * 20;                              // half2 index
    bool active = (g < 3);
    int2 rdv = rd[node];
    int rs = rdv.x, d = rdv.y;
    float ax = 0.f, ay = 0.f;
    if (g == 0) {                                        // self-loop
        float2 v = __half22float2(ZH[node * 32 + fl]);
        ax = v.x; ay = v.y;
    }
    if (active && d > 0) {
        int cl = d - 1;
        int k[5]; float w[5];
        // ---- round 1: 15 rows in flight wave-wide, covers j < 15 ----
#pragma unroll
        for (int t = 0; t < 5; ++t) {
            int jj = g + 3 * t;
            bool ok = jj < d;
            w[t] = ok ? 1.f : 0.f;
            k[t] = csr[rs + (ok ? jj : cl)];
        }
#pragma unroll
        for (int t = 0; t < 5; ++t) {
            float2 v = __half22float2(ZH[k[t] * 32 + fl]);
            ax = fmaf(w[t], v.x, ax);
            ay = fmaf(w[t], v.y, ay);
        }
        if (d > 15) {
            // ---- round 2: covers 15 <= j < 30 (~15.6% of waves) ----
#pragma unroll
            for (int t = 0; t < 5; ++t) {
                int jj = 15 + g + 3 * t;
                bool ok = jj < d;
                w[t] = ok ? 1.f : 0.f;
                k[t] = csr[rs + (ok ? jj : cl)];
            }
#pragma unroll
            for (int t = 0; t < 5; ++t) {
                float2 v = __half22float2(ZH[k[t] * 32 + fl]);
                ax = fmaf(w[t], v.x, ax);
                ay = fmaf(w[t], v.y, ay);
            }
            for (int j = 30 + g; j < d; j += 3) {   // safety tail, ~never
                float2 v = __half22float2(ZH[csr[rs + j] * 32 + fl]);
                ax += v.x; ay += v.y;
            }
        }
    }
    ax += __shfl(ax, (lane + 20) & 63) + __shfl(ax, (lane + 40) & 63);
    ay += __shfl(ay, (lane + 20) & 63) + __shfl(ay, (lane + 40) & 63);
    float vx = -INFINITY, vy = -INFINITY;
    if (lane < 20) {
        float2 bbv = b2[lane];
        vx = ax + bbv.x;
        vy = ay + bbv.y;
    }
    float m = fmaxf(vx, vy);
#pragma unroll
    for (int off = 16; off; off >>= 1) m = fmaxf(m, __shfl_xor(m, off));
    float ex = (lane < 20) ? __expf(vx - m) : 0.f;
    float ey = (lane < 20) ? __expf(vy - m) : 0.f;
    float ssum = ex + ey;
#pragma unroll
    for (int off = 16; off; off >>= 1) ssum += __shfl_xor(ssum, off);
    if (lane < 20) {
        float inv = 1.f / ssum;
        out[node * 20 + lane] = make_float2(ex * inv, ey * inv);
    }
}

extern "C" void kernel_launch(void* const* d_in, const int* in_sizes, int n_in,
                              void* d_out, int out_size, void* d_ws, size_t ws_size,
                              hipStream_t stream) {
    const float* h   = (const float*)d_in[0];   // N*D
    const int*   adj = (const int*)  d_in[1];   // E*2
    const float* W1  = (const float*)d_in[2];   // D*H
    const float* b1  = (const float*)d_in[3];   // H
    const float* W2  = (const float*)d_in[4];   // H*C
    const float* b2  = (const float*)d_in[5];   // C
    float* out = (float*)d_out;                 // N*C fp32

    // workspace (~87.7 MB), NO aliasing:
    //   agg1 fp32 N*64 | HH fp16 N*64 | XH fp16 N*128 | ZH fp16 N*64 | ints
    float*  agg1 = (float*)d_ws;                        // N*64 fp32
    __half* HH   = (__half*)(agg1 + (size_t)N * 64);    // N*64 fp16
    __half* XH   = HH + (size_t)N * 64;                 // N*128 fp16
    __half* ZH   = XH + (size_t)N * H;                  // N*64 fp16
    int* partial   = (int*)(ZH + (size_t)N * 64);       // NHB*NBUCK2
    int* obase     = partial + NHB * NBUCK2;            // NBUCK2*NHB
    int* btot      = obase + NBUCK2 * NHB;              // 128
    int* bstart    = btot + 128;                        // NBUCK2+1 (pad 128)
    int* staging   = bstart + 128;                      // E
    int* csr       = staging + E;                       // E
    int2* rd       = (int2*)(csr + E);                  // N (row_start, deg) — 8B aligned

    convert_h<<<N * 32 / (256 * 4), 256, 0, stream>>>((const float2*)h, (__half2*)HH);
    histo_b  <<<NHB, 256, 0, stream>>>((const int2*)adj, partial);
    scan_pb  <<<NBUCK2, 1024, 0, stream>>>(partial, obase, btot);
    scan_bt  <<<1, 128, 0, stream>>>(btot, bstart);
    append_b <<<NHB, 256, 0, stream>>>((const int2*)adj, bstart, obase, staging);
    fill_b   <<<NBUCK2, 1024, 0, stream>>>(staging, bstart, rd, csr);

    gather1        <<<N / 4, 256, 0, stream>>>((const __half2*)HH, csr, rd,
                                               (float2*)agg1);
    gemm1_relu     <<<N / 16, 256, 0, stream>>>(agg1, W1, b1, XH);
    gemm2          <<<(N + 63) / 64, 256, 0, stream>>>(XH, W2, ZH);
    gather2_softmax<<<N / 4, 256, 0, stream>>>((const __half2*)ZH, csr, rd,
                                               (const float2*)b2, (float2*)out);
}

// Round 3
// 235.165 us; speedup vs baseline: 1.1632x; 1.0719x over previous
//
#include <hip/hip_runtime.h>
#include <hip/hip_fp16.h>
#include <math.h>

// GCN: out = softmax( S·relu((S·h)W1 + b1) · W2 + b2 ),  S = in-edge sum + self-loop.
// Round 13: both gathers restructured to 4-nodes-per-wave, 16-lanes-per-node,
// SERIAL edge walk (feature-parallel only). Kills the per-node fixed overhead that
// R12's counters exposed (group-combine shuffles, 64-lane softmax with idle lanes):
// gather1 needs NO cross-lane reduce at all; gather2's softmax is a 16-lane masked
// reduce using the existing ZH zero-padding (rows already 128 B). Loop bound is the
// wave-max degree (uniform), batch-8 row loads in flight, clamp+weight predication.

constexpr int N = 100000;
constexpr int E = 1200000;
constexpr int D = 64;    // input dim
constexpr int H = 128;   // hidden
constexpr int C = 40;    // classes
constexpr int NBUCK2 = 98;                      // buckets of 1024 dst nodes
constexpr int EBLK   = 2048;                    // edges per histo/append block
constexpr int NHB    = (E + EBLK - 1) / EBLK;   // 586 edge blocks

// ---- h (fp32) -> HH (fp16), row = 64 halves = 128 B ----
__global__ __launch_bounds__(256) void convert_h(const float2* __restrict__ hf,
                                                 __half2* __restrict__ HH) {
    int i = (blockIdx.x * 256 + threadIdx.x) * 4;   // N*32 half2, exact
#pragma unroll
    for (int k = 0; k < 4; ++k) {
        float2 p = hf[i + k];
        HH[i + k] = __floats2half2_rn(p.x, p.y);
    }
}

// ---- per-block LDS bucket histogram (98 buckets), dense partial dump ----
__global__ __launch_bounds__(256) void histo_b(const int2* __restrict__ edges,
                                               int* __restrict__ partial) {
    __shared__ int cnt[NBUCK2];
    if (threadIdx.x < NBUCK2) cnt[threadIdx.x] = 0;
    __syncthreads();
    int base = blockIdx.x * EBLK + threadIdx.x * 8;
#pragma unroll
    for (int i = 0; i < 8; ++i) {
        int e = base + i;
        if (e < E) atomicAdd(&cnt[edges[e].y >> 10], 1);
    }
    __syncthreads();
    if (threadIdx.x < NBUCK2)
        partial[blockIdx.x * NBUCK2 + threadIdx.x] = cnt[threadIdx.x];
}

// ---- per-bucket column scan of partial: obase[b][blk], btot[b] ----
__global__ __launch_bounds__(1024) void scan_pb(const int* __restrict__ partial,
                                                int* __restrict__ obase,
                                                int* __restrict__ btot) {
    __shared__ int s[1024];
    int b = blockIdx.x, t = threadIdx.x;
    int v = (t < NHB) ? partial[t * NBUCK2 + b] : 0;
    s[t] = v;
    __syncthreads();
    for (int off = 1; off < 1024; off <<= 1) {
        int x = (t >= off) ? s[t - off] : 0;
        __syncthreads();
        s[t] += x;
        __syncthreads();
    }
    if (t < NHB) obase[b * NHB + t] = s[t] - v;   // exclusive within bucket
    if (t == 1023) btot[b] = s[1023];
}

// ---- exclusive scan of bucket totals -> bstart[0..NBUCK2] ----
__global__ __launch_bounds__(128) void scan_bt(const int* __restrict__ btot,
                                               int* __restrict__ bstart) {
    __shared__ int s[128];
    int t = threadIdx.x;
    int v = (t < NBUCK2) ? btot[t] : 0;
    s[t] = v;
    __syncthreads();
    for (int off = 1; off < 128; off <<= 1) {
        int x = (t >= off) ? s[t - off] : 0;
        __syncthreads();
        s[t] += x;
        __syncthreads();
    }
    if (t < NBUCK2) bstart[t] = s[t] - v;
    if (t == NBUCK2 - 1) bstart[NBUCK2] = s[t];   // = E
}

// ---- append: deterministic positions, LDS cursors seeded from scanned bases ----
__global__ __launch_bounds__(256) void append_b(const int2* __restrict__ edges,
                                                const int* __restrict__ bstart,
                                                const int* __restrict__ obase,
                                                int* __restrict__ staging) {
    __shared__ int cur[NBUCK2];
    int blk = blockIdx.x;
    if (threadIdx.x < NBUCK2)
        cur[threadIdx.x] = bstart[threadIdx.x] + obase[threadIdx.x * NHB + blk];
    __syncthreads();
    int base = blk * EBLK + threadIdx.x * 8;
#pragma unroll
    for (int i = 0; i < 8; ++i) {
        int e = base + i;
        if (e < E) {
            int2 ed = edges[e];
            int b = ed.y >> 10;
            int p = atomicAdd(&cur[b], 1);               // LDS atomic
            staging[p] = (ed.x << 10) | (ed.y & 1023);   // src:17b | dst_local:10b
        }
    }
}

// ---- per-bucket: LDS count + scan -> rd(row_start,deg), scatter csr in window ----
__global__ __launch_bounds__(1024) void fill_b(const int* __restrict__ staging,
                                               const int* __restrict__ bstart,
                                               int2* __restrict__ rd,
                                               int* __restrict__ csr) {
    __shared__ int cnt[1024], s[1024], cur[1024];
    int b = blockIdx.x, t = threadIdx.x;
    cnt[t] = 0;
    __syncthreads();
    int lo = bstart[b], hi = bstart[b + 1];
    for (int i = lo + t; i < hi; i += 1024)
        atomicAdd(&cnt[staging[i] & 1023], 1);
    __syncthreads();
    int v = cnt[t];
    s[t] = v;
    __syncthreads();
    for (int off = 1; off < 1024; off <<= 1) {
        int x = (t >= off) ? s[t - off] : 0;
        __syncthreads();
        s[t] += x;
        __syncthreads();
    }
    int ex = s[t] - v;
    cur[t] = ex;
    int node = (b << 10) + t;
    if (node < N) rd[node] = make_int2(lo + ex, v);
    __syncthreads();
    for (int i = lo + t; i < hi; i += 1024) {
        int w = staging[i];
        int p = atomicAdd(&cur[w & 1023], 1);
        csr[lo + p] = w >> 10;
    }
}

// ---- layer-1 gather: 4 nodes/wave, 16 lanes/node (8B of the 128B row each),
//      serial edge walk to wave-max degree, batch-8, NO cross-lane reduce ----
__global__ __launch_bounds__(256) void gather1(const __half2* __restrict__ HH,
                                               const int* __restrict__ csr,
                                               const int2* __restrict__ rd,
                                               float4* __restrict__ agg) {
    int node = blockIdx.x * 16 + (threadIdx.x >> 4);
    int fl = threadIdx.x & 15;
    const float2* H4 = (const float2*)HH;     // row = 16 float2 = 128 B
    int2 rdv = rd[node];
    int rs = rdv.x, d = rdv.y;
    if (d == 0) rs = 0;                        // safe dummy window
    int cl = (d > 0) ? d - 1 : 0;
    int dmax = d;                              // wave-uniform loop bound
    dmax = max(dmax, __shfl_xor(dmax, 16));
    dmax = max(dmax, __shfl_xor(dmax, 32));
    float a0, a1, a2, a3;
    {   // self-loop init
        float2 raw = H4[node * 16 + fl];
        const __half2* hp = (const __half2*)&raw;
        float2 v0 = __half22float2(hp[0]), v1 = __half22float2(hp[1]);
        a0 = v0.x; a1 = v0.y; a2 = v1.x; a3 = v1.y;
    }
    for (int j0 = 0; j0 < dmax; j0 += 8) {     // 8 rows in flight per node
        int k[8]; float w[8];
#pragma unroll
        for (int t = 0; t < 8; ++t) {
            int jj = j0 + t;
            bool ok = jj < d;
            w[t] = ok ? 1.f : 0.f;
            k[t] = csr[rs + (ok ? jj : cl)];
        }
#pragma unroll
        for (int t = 0; t < 8; ++t) {
            float2 raw = H4[k[t] * 16 + fl];
            const __half2* hp = (const __half2*)&raw;
            float2 v0 = __half22float2(hp[0]), v1 = __half22float2(hp[1]);
            a0 = fmaf(w[t], v0.x, a0); a1 = fmaf(w[t], v0.y, a1);
            a2 = fmaf(w[t], v1.x, a2); a3 = fmaf(w[t], v1.y, a3);
        }
    }
    agg[node * 16 + fl] = make_float4(a0, a1, a2, a3);   // features 4fl..4fl+3
}

// ---- XH = fp16(relu(agg @ W1 + b1)), tiled ----
__global__ __launch_bounds__(256) void gemm1_relu(const float* __restrict__ A,
                                                  const float* __restrict__ W1,
                                                  const float* __restrict__ b1,
                                                  __half* __restrict__ XH) {
    __shared__ float w_s[D * H];      // 32 KB
    __shared__ float a_s[16 * D];     // 4 KB
    int row0 = blockIdx.x * 16;
    {
        const float4* src = (const float4*)W1;
        float4* dst = (float4*)w_s;
#pragma unroll
        for (int i = 0; i < 8; ++i)
            dst[threadIdx.x + i * 256] = src[threadIdx.x + i * 256];
    }
    {
        int r = threadIdx.x >> 4;
        int q = threadIdx.x & 15;
        float4 v = *(const float4*)&A[(row0 + r) * D + q * 4];
        *(float4*)&a_s[r * D + q * 4] = v;
    }
    __syncthreads();

    int tr   = threadIdx.x >> 6;
    int lane = threadIdx.x & 63;
    float acc[4][2] = {};
#pragma unroll
    for (int k = 0; k < D; ++k) {
        float b0 = w_s[k * H + lane];
        float b1v = w_s[k * H + lane + 64];
#pragma unroll
        for (int i = 0; i < 4; ++i) {
            float a = a_s[(tr + 4 * i) * D + k];
            acc[i][0] = fmaf(a, b0, acc[i][0]);
            acc[i][1] = fmaf(a, b1v, acc[i][1]);
        }
    }
    float bias0 = b1[lane], bias1 = b1[lane + 64];
#pragma unroll
    for (int i = 0; i < 4; ++i) {
        int row = row0 + tr + 4 * i;
        XH[row * H + lane]      = __float2half_rn(fmaxf(acc[i][0] + bias0, 0.f));
        XH[row * H + lane + 64] = __float2half_rn(fmaxf(acc[i][1] + bias1, 0.f));
    }
}

// ---- ZH = fp16(XH @ W2), row stride 64 halves, cols 40..63 zero-filled ----
constexpr int XS = 132;
__global__ __launch_bounds__(256) void gemm2(const __half* __restrict__ XH,
                                             const float* __restrict__ W2,
                                             __half* __restrict__ ZH) {
    __shared__ float w_s[H * C];        // 20 KB
    __shared__ float x_s[64 * XS];      // 33.8 KB
    int row0 = blockIdx.x * 64;
    {
        const float4* src = (const float4*)W2;
        float4* dst = (float4*)w_s;
#pragma unroll
        for (int i = 0; i < 5; ++i)
            dst[threadIdx.x + i * 256] = src[threadIdx.x + i * 256];
    }
    {   // stage XH (fp16) -> x_s (fp32): 64 rows x 16 chunks of 8 halves
#pragma unroll
        for (int i = 0; i < 4; ++i) {
            int idx = threadIdx.x + i * 256;   // 1024 chunks
            int r = idx >> 4;
            int q = idx & 15;
            int grow = row0 + r;
            if (grow >= N) grow = N - 1;
            float4 raw = *(const float4*)&XH[grow * H + q * 8];
            __half2* hp = (__half2*)&raw;
            float2 f0 = __half22float2(hp[0]), f1 = __half22float2(hp[1]);
            float2 f2 = __half22float2(hp[2]), f3 = __half22float2(hp[3]);
            float* dst = &x_s[r * XS + q * 8];
            dst[0] = f0.x; dst[1] = f0.y; dst[2] = f1.x; dst[3] = f1.y;
            dst[4] = f2.x; dst[5] = f2.y; dst[6] = f3.x; dst[7] = f3.y;
        }
    }
    __syncthreads();

    int tc   = threadIdx.x & 7;         // cols tc*5 .. tc*5+4
    int trow = threadIdx.x >> 3;        // rows trow*2, trow*2+1
    float acc[2][5] = {};
#pragma unroll 4
    for (int k = 0; k < H; ++k) {
        float b[5];
#pragma unroll
        for (int j = 0; j < 5; ++j) b[j] = w_s[k * C + tc * 5 + j];
        float a0 = x_s[(trow * 2) * XS + k];
        float a1 = x_s[(trow * 2 + 1) * XS + k];
#pragma unroll
        for (int j = 0; j < 5; ++j) {
            acc[0][j] = fmaf(a0, b[j], acc[0][j]);
            acc[1][j] = fmaf(a1, b[j], acc[1][j]);
        }
    }
#pragma unroll
    for (int i = 0; i < 2; ++i) {
        int row = row0 + trow * 2 + i;
        if (row < N) {
#pragma unroll
            for (int j = 0; j < 5; ++j)
                ZH[row * 64 + tc * 5 + j] = __float2half_rn(acc[i][j]);
#pragma unroll
            for (int j = 0; j < 3; ++j)          // pad cols 40..63
                ZH[row * 64 + 40 + tc * 3 + j] = __half(0.f);
        }
    }
}

// ---- out[node] = softmax(Z[node] + sum Z[src] + b2): 4 nodes/wave, 16 lanes/node.
//      Lanes fl>=10 carry the zero-pad cols; -inf mask makes exp->0 so only the
//      max needs masking. 16-lane xor reduces; float4 store for fl<10. ----
__global__ __launch_bounds__(256) void gather2_softmax(const __half2* __restrict__ ZH,
                                                       const int* __restrict__ csr,
                                                       const int2* __restrict__ rd,
                                                       const float* __restrict__ b2,
                                                       float4* __restrict__ out) {
    int node = blockIdx.x * 16 + (threadIdx.x >> 4);
    int fl = threadIdx.x & 15;
    const float2* Z4 = (const float2*)ZH;     // row = 16 float2 = 128 B (padded)
    int2 rdv = rd[node];
    int rs = rdv.x, d = rdv.y;
    if (d == 0) rs = 0;
    int cl = (d > 0) ? d - 1 : 0;
    int dmax = d;
    dmax = max(dmax, __shfl_xor(dmax, 16));
    dmax = max(dmax, __shfl_xor(dmax, 32));
    float a0, a1, a2, a3;
    {   // self-loop init
        float2 raw = Z4[node * 16 + fl];
        const __half2* hp = (const __half2*)&raw;
        float2 v0 = __half22float2(hp[0]), v1 = __half22float2(hp[1]);
        a0 = v0.x; a1 = v0.y; a2 = v1.x; a3 = v1.y;
    }
    for (int j0 = 0; j0 < dmax; j0 += 8) {
        int k[8]; float w[8];
#pragma unroll
        for (int t = 0; t < 8; ++t) {
            int jj = j0 + t;
            bool ok = jj < d;
            w[t] = ok ? 1.f : 0.f;
            k[t] = csr[rs + (ok ? jj : cl)];
        }
#pragma unroll
        for (int t = 0; t < 8; ++t) {
            float2 raw = Z4[k[t] * 16 + fl];
            const __half2* hp = (const __half2*)&raw;
            float2 v0 = __half22float2(hp[0]), v1 = __half22float2(hp[1]);
            a0 = fmaf(w[t], v0.x, a0); a1 = fmaf(w[t], v0.y, a1);
            a2 = fmaf(w[t], v1.x, a2); a3 = fmaf(w[t], v1.y, a3);
        }
    }
    // softmax over the 40 real cols (lanes fl<10, cols 4fl..4fl+3)
    const float4* b4 = (const float4*)b2;
    bool real = fl < 10;
    float4 bb = b4[real ? fl : 9];
    float v0 = real ? a0 + bb.x : -INFINITY;
    float v1 = real ? a1 + bb.y : -INFINITY;
    float v2 = real ? a2 + bb.z : -INFINITY;
    float v3 = real ? a3 + bb.w : -INFINITY;
    float m = fmaxf(fmaxf(v0, v1), fmaxf(v2, v3));
#pragma unroll
    for (int off = 1; off < 16; off <<= 1) m = fmaxf(m, __shfl_xor(m, off));
    float e0 = __expf(v0 - m), e1 = __expf(v1 - m);   // -inf lanes -> exp = 0
    float e2 = __expf(v2 - m), e3 = __expf(v3 - m);
    float s = (e0 + e1) + (e2 + e3);
#pragma unroll
    for (int off = 1; off < 16; off <<= 1) s += __shfl_xor(s, off);
    float inv = 1.f / s;
    if (real)
        out[node * 10 + fl] = make_float4(e0 * inv, e1 * inv, e2 * inv, e3 * inv);
}

extern "C" void kernel_launch(void* const* d_in, const int* in_sizes, int n_in,
                              void* d_out, int out_size, void* d_ws, size_t ws_size,
                              hipStream_t stream) {
    const float* h   = (const float*)d_in[0];   // N*D
    const int*   adj = (const int*)  d_in[1];   // E*2
    const float* W1  = (const float*)d_in[2];   // D*H
    const float* b1  = (const float*)d_in[3];   // H
    const float* W2  = (const float*)d_in[4];   // H*C
    const float* b2  = (const float*)d_in[5];   // C
    float* out = (float*)d_out;                 // N*C fp32

    // workspace (~87.7 MB), NO aliasing:
    //   agg1 fp32 N*64 | HH fp16 N*64 | XH fp16 N*128 | ZH fp16 N*64 | ints
    float*  agg1 = (float*)d_ws;                        // N*64 fp32
    __half* HH   = (__half*)(agg1 + (size_t)N * 64);    // N*64 fp16
    __half* XH   = HH + (size_t)N * 64;                 // N*128 fp16
    __half* ZH   = XH + (size_t)N * H;                  // N*64 fp16
    int* partial   = (int*)(ZH + (size_t)N * 64);       // NHB*NBUCK2
    int* obase     = partial + NHB * NBUCK2;            // NBUCK2*NHB
    int* btot      = obase + NBUCK2 * NHB;              // 128
    int* bstart    = btot + 128;                        // NBUCK2+1 (pad 128)
    int* staging   = bstart + 128;                      // E
    int* csr       = staging + E;                       // E
    int2* rd       = (int2*)(csr + E);                  // N (row_start, deg) — 8B aligned

    convert_h<<<N * 32 / (256 * 4), 256, 0, stream>>>((const float2*)h, (__half2*)HH);
    histo_b  <<<NHB, 256, 0, stream>>>((const int2*)adj, partial);
    scan_pb  <<<NBUCK2, 1024, 0, stream>>>(partial, obase, btot);
    scan_bt  <<<1, 128, 0, stream>>>(btot, bstart);
    append_b <<<NHB, 256, 0, stream>>>((const int2*)adj, bstart, obase, staging);
    fill_b   <<<NBUCK2, 1024, 0, stream>>>(staging, bstart, rd, csr);

    gather1        <<<N / 16, 256, 0, stream>>>((const __half2*)HH, csr, rd,
                                                (float4*)agg1);
    gemm1_relu     <<<N / 16, 256, 0, stream>>>(agg1, W1, b1, XH);
    gemm2          <<<(N + 63) / 64, 256, 0, stream>>>(XH, W2, ZH);
    gather2_softmax<<<N / 16, 256, 0, stream>>>((const __half2*)ZH, csr, rd,
                                                b2, (float4*)out);
}

// Round 4
// 218.123 us; speedup vs baseline: 1.2541x; 1.0781x over previous
//
#include <hip/hip_runtime.h>
#include <hip/hip_fp16.h>
#include <math.h>

// GCN: out = softmax( S·relu((S·h)W1 + b1) · W2 + b2 ),  S = in-edge sum + self-loop.
// Round 14: FUSE gather1 + gemm1_relu (same 16-node/256-thread block geometry) via
// a 4 KB LDS handoff — kills the 51 MB agg1 HBM round-trip. W1 staged in LDS as
// fp16 column-pairs (16 KB) so total LDS = 20.5 KB -> 8 blocks/CU (full occupancy
// for the latency-bound gather phase). convert_h folded into histo_b (one less
// launch). Everything else unchanged from round 13.

constexpr int N = 100000;
constexpr int E = 1200000;
constexpr int D = 64;    // input dim
constexpr int H = 128;   // hidden
constexpr int C = 40;    // classes
constexpr int NBUCK2 = 98;                      // buckets of 1024 dst nodes
constexpr int EBLK   = 2048;                    // edges per histo/append block
constexpr int NHB    = (E + EBLK - 1) / EBLK;   // 586 edge blocks

// ---- histo (98 buckets) + grid-stride h->fp16 convert prologue ----
__global__ __launch_bounds__(256) void histo_conv(const int2* __restrict__ edges,
                                                  int* __restrict__ partial,
                                                  const float2* __restrict__ hf,
                                                  __half2* __restrict__ HH) {
    __shared__ int cnt[NBUCK2];
    if (threadIdx.x < NBUCK2) cnt[threadIdx.x] = 0;
    // convert h (N*32 half2) while histo LDS settles; independent data
    for (int i = blockIdx.x * 256 + threadIdx.x; i < N * 32; i += NHB * 256) {
        float2 p = hf[i];
        HH[i] = __floats2half2_rn(p.x, p.y);
    }
    __syncthreads();
    int base = blockIdx.x * EBLK + threadIdx.x * 8;
#pragma unroll
    for (int i = 0; i < 8; ++i) {
        int e = base + i;
        if (e < E) atomicAdd(&cnt[edges[e].y >> 10], 1);
    }
    __syncthreads();
    if (threadIdx.x < NBUCK2)
        partial[blockIdx.x * NBUCK2 + threadIdx.x] = cnt[threadIdx.x];
}

// ---- per-bucket column scan of partial: obase[b][blk], btot[b] ----
__global__ __launch_bounds__(1024) void scan_pb(const int* __restrict__ partial,
                                                int* __restrict__ obase,
                                                int* __restrict__ btot) {
    __shared__ int s[1024];
    int b = blockIdx.x, t = threadIdx.x;
    int v = (t < NHB) ? partial[t * NBUCK2 + b] : 0;
    s[t] = v;
    __syncthreads();
    for (int off = 1; off < 1024; off <<= 1) {
        int x = (t >= off) ? s[t - off] : 0;
        __syncthreads();
        s[t] += x;
        __syncthreads();
    }
    if (t < NHB) obase[b * NHB + t] = s[t] - v;   // exclusive within bucket
    if (t == 1023) btot[b] = s[1023];
}

// ---- exclusive scan of bucket totals -> bstart[0..NBUCK2] ----
__global__ __launch_bounds__(128) void scan_bt(const int* __restrict__ btot,
                                               int* __restrict__ bstart) {
    __shared__ int s[128];
    int t = threadIdx.x;
    int v = (t < NBUCK2) ? btot[t] : 0;
    s[t] = v;
    __syncthreads();
    for (int off = 1; off < 128; off <<= 1) {
        int x = (t >= off) ? s[t - off] : 0;
        __syncthreads();
        s[t] += x;
        __syncthreads();
    }
    if (t < NBUCK2) bstart[t] = s[t] - v;
    if (t == NBUCK2 - 1) bstart[NBUCK2] = s[t];   // = E
}

// ---- append: deterministic positions, LDS cursors seeded from scanned bases ----
__global__ __launch_bounds__(256) void append_b(const int2* __restrict__ edges,
                                                const int* __restrict__ bstart,
                                                const int* __restrict__ obase,
                                                int* __restrict__ staging) {
    __shared__ int cur[NBUCK2];
    int blk = blockIdx.x;
    if (threadIdx.x < NBUCK2)
        cur[threadIdx.x] = bstart[threadIdx.x] + obase[threadIdx.x * NHB + blk];
    __syncthreads();
    int base = blk * EBLK + threadIdx.x * 8;
#pragma unroll
    for (int i = 0; i < 8; ++i) {
        int e = base + i;
        if (e < E) {
            int2 ed = edges[e];
            int b = ed.y >> 10;
            int p = atomicAdd(&cur[b], 1);               // LDS atomic
            staging[p] = (ed.x << 10) | (ed.y & 1023);   // src:17b | dst_local:10b
        }
    }
}

// ---- per-bucket: LDS count + scan -> rd(row_start,deg), scatter csr in window ----
__global__ __launch_bounds__(1024) void fill_b(const int* __restrict__ staging,
                                               const int* __restrict__ bstart,
                                               int2* __restrict__ rd,
                                               int* __restrict__ csr) {
    __shared__ int cnt[1024], s[1024], cur[1024];
    int b = blockIdx.x, t = threadIdx.x;
    cnt[t] = 0;
    __syncthreads();
    int lo = bstart[b], hi = bstart[b + 1];
    for (int i = lo + t; i < hi; i += 1024)
        atomicAdd(&cnt[staging[i] & 1023], 1);
    __syncthreads();
    int v = cnt[t];
    s[t] = v;
    __syncthreads();
    for (int off = 1; off < 1024; off <<= 1) {
        int x = (t >= off) ? s[t - off] : 0;
        __syncthreads();
        s[t] += x;
        __syncthreads();
    }
    int ex = s[t] - v;
    cur[t] = ex;
    int node = (b << 10) + t;
    if (node < N) rd[node] = make_int2(lo + ex, v);
    __syncthreads();
    for (int i = lo + t; i < hi; i += 1024) {
        int w = staging[i];
        int p = atomicAdd(&cur[w & 1023], 1);
        csr[lo + p] = w >> 10;
    }
}

// ---- FUSED layer 1: gather (4 nodes/wave, 16 lanes/node, batch-8) -> LDS a_s,
//      then XH = fp16(relu(a_s @ W1 + b1)). W1 in LDS as fp16 col-pairs (16 KB);
//      total LDS 20.5 KB -> 8 blocks/CU. 16 nodes per block. ----
__global__ __launch_bounds__(256) void fused1(const __half2* __restrict__ HH,
                                              const int* __restrict__ csr,
                                              const int2* __restrict__ rd,
                                              const float* __restrict__ W1,
                                              const float* __restrict__ b1,
                                              __half* __restrict__ XH) {
    __shared__ __half2 w_h[D * 64];   // [k][c] = (W1[k][c], W1[k][c+64]), 16 KB
    __shared__ float a_s[16 * D];     // 4 KB
    // stage W1 -> fp16 swizzled column pairs
#pragma unroll
    for (int i = 0; i < 16; ++i) {
        int idx = threadIdx.x + i * 256;   // 4096 = 64k * 64c
        int k = idx >> 6, c = idx & 63;
        w_h[idx] = __floats2half2_rn(W1[k * H + c], W1[k * H + c + 64]);
    }
    // ---- gather phase ----
    int node = blockIdx.x * 16 + (threadIdx.x >> 4);
    int fl = threadIdx.x & 15;
    const float2* H4 = (const float2*)HH;     // row = 16 float2 = 128 B
    int2 rdv = rd[node];
    int rs = rdv.x, d = rdv.y;
    if (d == 0) rs = 0;                        // safe dummy window
    int cl = (d > 0) ? d - 1 : 0;
    int dmax = d;                              // wave-uniform loop bound
    dmax = max(dmax, __shfl_xor(dmax, 16));
    dmax = max(dmax, __shfl_xor(dmax, 32));
    float a0, a1, a2, a3;
    {   // self-loop init
        float2 raw = H4[node * 16 + fl];
        const __half2* hp = (const __half2*)&raw;
        float2 v0 = __half22float2(hp[0]), v1 = __half22float2(hp[1]);
        a0 = v0.x; a1 = v0.y; a2 = v1.x; a3 = v1.y;
    }
    for (int j0 = 0; j0 < dmax; j0 += 8) {     // 8 rows in flight per node
        int k[8]; float w[8];
#pragma unroll
        for (int t = 0; t < 8; ++t) {
            int jj = j0 + t;
            bool ok = jj < d;
            w[t] = ok ? 1.f : 0.f;
            k[t] = csr[rs + (ok ? jj : cl)];
        }
#pragma unroll
        for (int t = 0; t < 8; ++t) {
            float2 raw = H4[k[t] * 16 + fl];
            const __half2* hp = (const __half2*)&raw;
            float2 v0 = __half22float2(hp[0]), v1 = __half22float2(hp[1]);
            a0 = fmaf(w[t], v0.x, a0); a1 = fmaf(w[t], v0.y, a1);
            a2 = fmaf(w[t], v1.x, a2); a3 = fmaf(w[t], v1.y, a3);
        }
    }
    *(float4*)&a_s[(threadIdx.x >> 4) * D + fl * 4] = make_float4(a0, a1, a2, a3);
    __syncthreads();
    // ---- gemm phase (16 rows x 128 cols) ----
    int tr   = threadIdx.x >> 6;
    int lane = threadIdx.x & 63;
    float acc[4][2] = {};
#pragma unroll
    for (int k = 0; k < D; ++k) {
        float2 b01 = __half22float2(w_h[k * 64 + lane]);   // cols lane, lane+64
#pragma unroll
        for (int i = 0; i < 4; ++i) {
            float a = a_s[(tr + 4 * i) * D + k];
            acc[i][0] = fmaf(a, b01.x, acc[i][0]);
            acc[i][1] = fmaf(a, b01.y, acc[i][1]);
        }
    }
    int row0 = blockIdx.x * 16;
    float bias0 = b1[lane], bias1 = b1[lane + 64];
#pragma unroll
    for (int i = 0; i < 4; ++i) {
        int row = row0 + tr + 4 * i;
        XH[row * H + lane]      = __float2half_rn(fmaxf(acc[i][0] + bias0, 0.f));
        XH[row * H + lane + 64] = __float2half_rn(fmaxf(acc[i][1] + bias1, 0.f));
    }
}

// ---- ZH = fp16(XH @ W2), row stride 64 halves, cols 40..63 zero-filled ----
constexpr int XS = 132;
__global__ __launch_bounds__(256) void gemm2(const __half* __restrict__ XH,
                                             const float* __restrict__ W2,
                                             __half* __restrict__ ZH) {
    __shared__ float w_s[H * C];        // 20 KB
    __shared__ float x_s[64 * XS];      // 33.8 KB
    int row0 = blockIdx.x * 64;
    {
        const float4* src = (const float4*)W2;
        float4* dst = (float4*)w_s;
#pragma unroll
        for (int i = 0; i < 5; ++i)
            dst[threadIdx.x + i * 256] = src[threadIdx.x + i * 256];
    }
    {   // stage XH (fp16) -> x_s (fp32): 64 rows x 16 chunks of 8 halves
#pragma unroll
        for (int i = 0; i < 4; ++i) {
            int idx = threadIdx.x + i * 256;   // 1024 chunks
            int r = idx >> 4;
            int q = idx & 15;
            int grow = row0 + r;
            if (grow >= N) grow = N - 1;
            float4 raw = *(const float4*)&XH[grow * H + q * 8];
            __half2* hp = (__half2*)&raw;
            float2 f0 = __half22float2(hp[0]), f1 = __half22float2(hp[1]);
            float2 f2 = __half22float2(hp[2]), f3 = __half22float2(hp[3]);
            float* dst = &x_s[r * XS + q * 8];
            dst[0] = f0.x; dst[1] = f0.y; dst[2] = f1.x; dst[3] = f1.y;
            dst[4] = f2.x; dst[5] = f2.y; dst[6] = f3.x; dst[7] = f3.y;
        }
    }
    __syncthreads();

    int tc   = threadIdx.x & 7;         // cols tc*5 .. tc*5+4
    int trow = threadIdx.x >> 3;        // rows trow*2, trow*2+1
    float acc[2][5] = {};
#pragma unroll 4
    for (int k = 0; k < H; ++k) {
        float b[5];
#pragma unroll
        for (int j = 0; j < 5; ++j) b[j] = w_s[k * C + tc * 5 + j];
        float a0 = x_s[(trow * 2) * XS + k];
        float a1 = x_s[(trow * 2 + 1) * XS + k];
#pragma unroll
        for (int j = 0; j < 5; ++j) {
            acc[0][j] = fmaf(a0, b[j], acc[0][j]);
            acc[1][j] = fmaf(a1, b[j], acc[1][j]);
        }
    }
#pragma unroll
    for (int i = 0; i < 2; ++i) {
        int row = row0 + trow * 2 + i;
        if (row < N) {
#pragma unroll
            for (int j = 0; j < 5; ++j)
                ZH[row * 64 + tc * 5 + j] = __float2half_rn(acc[i][j]);
#pragma unroll
            for (int j = 0; j < 3; ++j)          // pad cols 40..63
                ZH[row * 64 + 40 + tc * 3 + j] = __half(0.f);
        }
    }
}

// ---- out[node] = softmax(Z[node] + sum Z[src] + b2): 4 nodes/wave, 16 lanes/node.
//      Lanes fl>=10 carry the zero-pad cols; -inf mask makes exp->0 so only the
//      max needs masking. 16-lane xor reduces; float4 store for fl<10. ----
__global__ __launch_bounds__(256) void gather2_softmax(const __half2* __restrict__ ZH,
                                                       const int* __restrict__ csr,
                                                       const int2* __restrict__ rd,
                                                       const float* __restrict__ b2,
                                                       float4* __restrict__ out) {
    int node = blockIdx.x * 16 + (threadIdx.x >> 4);
    int fl = threadIdx.x & 15;
    const float2* Z4 = (const float2*)ZH;     // row = 16 float2 = 128 B (padded)
    int2 rdv = rd[node];
    int rs = rdv.x, d = rdv.y;
    if (d == 0) rs = 0;
    int cl = (d > 0) ? d - 1 : 0;
    int dmax = d;
    dmax = max(dmax, __shfl_xor(dmax, 16));
    dmax = max(dmax, __shfl_xor(dmax, 32));
    float a0, a1, a2, a3;
    {   // self-loop init
        float2 raw = Z4[node * 16 + fl];
        const __half2* hp = (const __half2*)&raw;
        float2 v0 = __half22float2(hp[0]), v1 = __half22float2(hp[1]);
        a0 = v0.x; a1 = v0.y; a2 = v1.x; a3 = v1.y;
    }
    for (int j0 = 0; j0 < dmax; j0 += 8) {
        int k[8]; float w[8];
#pragma unroll
        for (int t = 0; t < 8; ++t) {
            int jj = j0 + t;
            bool ok = jj < d;
            w[t] = ok ? 1.f : 0.f;
            k[t] = csr[rs + (ok ? jj : cl)];
        }
#pragma unroll
        for (int t = 0; t < 8; ++t) {
            float2 raw = Z4[k[t] * 16 + fl];
            const __half2* hp = (const __half2*)&raw;
            float2 v0 = __half22float2(hp[0]), v1 = __half22float2(hp[1]);
            a0 = fmaf(w[t], v0.x, a0); a1 = fmaf(w[t], v0.y, a1);
            a2 = fmaf(w[t], v1.x, a2); a3 = fmaf(w[t], v1.y, a3);
        }
    }
    // softmax over the 40 real cols (lanes fl<10, cols 4fl..4fl+3)
    const float4* b4 = (const float4*)b2;
    bool real = fl < 10;
    float4 bb = b4[real ? fl : 9];
    float v0 = real ? a0 + bb.x : -INFINITY;
    float v1 = real ? a1 + bb.y : -INFINITY;
    float v2 = real ? a2 + bb.z : -INFINITY;
    float v3 = real ? a3 + bb.w : -INFINITY;
    float m = fmaxf(fmaxf(v0, v1), fmaxf(v2, v3));
#pragma unroll
    for (int off = 1; off < 16; off <<= 1) m = fmaxf(m, __shfl_xor(m, off));
    float e0 = __expf(v0 - m), e1 = __expf(v1 - m);   // -inf lanes -> exp = 0
    float e2 = __expf(v2 - m), e3 = __expf(v3 - m);
    float s = (e0 + e1) + (e2 + e3);
#pragma unroll
    for (int off = 1; off < 16; off <<= 1) s += __shfl_xor(s, off);
    float inv = 1.f / s;
    if (real)
        out[node * 10 + fl] = make_float4(e0 * inv, e1 * inv, e2 * inv, e3 * inv);
}

extern "C" void kernel_launch(void* const* d_in, const int* in_sizes, int n_in,
                              void* d_out, int out_size, void* d_ws, size_t ws_size,
                              hipStream_t stream) {
    const float* h   = (const float*)d_in[0];   // N*D
    const int*   adj = (const int*)  d_in[1];   // E*2
    const float* W1  = (const float*)d_in[2];   // D*H
    const float* b1  = (const float*)d_in[3];   // H
    const float* W2  = (const float*)d_in[4];   // H*C
    const float* b2  = (const float*)d_in[5];   // C
    float* out = (float*)d_out;                 // N*C fp32

    // workspace, NO aliasing (agg1 slot retained but unused after fusion):
    //   agg1 fp32 N*64 | HH fp16 N*64 | XH fp16 N*128 | ZH fp16 N*64 | ints
    float*  agg1 = (float*)d_ws;                        // N*64 fp32 (unused)
    __half* HH   = (__half*)(agg1 + (size_t)N * 64);    // N*64 fp16
    __half* XH   = HH + (size_t)N * 64;                 // N*128 fp16
    __half* ZH   = XH + (size_t)N * H;                  // N*64 fp16
    int* partial   = (int*)(ZH + (size_t)N * 64);       // NHB*NBUCK2
    int* obase     = partial + NHB * NBUCK2;            // NBUCK2*NHB
    int* btot      = obase + NBUCK2 * NHB;              // 128
    int* bstart    = btot + 128;                        // NBUCK2+1 (pad 128)
    int* staging   = bstart + 128;                      // E
    int* csr       = staging + E;                       // E
    int2* rd       = (int2*)(csr + E);                  // N (row_start, deg)

    histo_conv<<<NHB, 256, 0, stream>>>((const int2*)adj, partial,
                                        (const float2*)h, (__half2*)HH);
    scan_pb   <<<NBUCK2, 1024, 0, stream>>>(partial, obase, btot);
    scan_bt   <<<1, 128, 0, stream>>>(btot, bstart);
    append_b  <<<NHB, 256, 0, stream>>>((const int2*)adj, bstart, obase, staging);
    fill_b    <<<NBUCK2, 1024, 0, stream>>>(staging, bstart, rd, csr);

    fused1         <<<N / 16, 256, 0, stream>>>((const __half2*)HH, csr, rd,
                                                W1, b1, XH);
    gemm2          <<<(N + 63) / 64, 256, 0, stream>>>(XH, W2, ZH);
    gather2_softmax<<<N / 16, 256, 0, stream>>>((const __half2*)ZH, csr, rd,
                                                b2, (float4*)out);
}

// Round 5
// 210.646 us; speedup vs baseline: 1.2986x; 1.0355x over previous
//
#include <hip/hip_runtime.h>
#include <hip/hip_fp16.h>
#include <math.h>

// GCN: out = softmax( S·relu((S·h)W1 + b1) · W2 + b2 ),  S = in-edge sum + self-loop.
// Round 15: fused1's gemm phase moved from vector-ALU (~900 VALU ops/thread) to
// MFMA 16x16x32_f16 (4 MFMAs/wave). Gather writes fp16 -> 2.3 KB LDS a_h[16][72]
// (stride 72 halves = 144 B: 16B-aligned b128 frag reads, conflict-light).
// W1 pre-packed ONCE into fragment-ordered fp16 (prep_w1, 4 blocks, stored in the
// dead agg1 ws slot) -> fused1 has no W1 staging at all. A/B packing uses the same
// (lane-group,reg)->k map (contiguous 8 per group) so k-permutation cancels; C/D
// layout is the verified col=lane&15, row=(lane>>4)*4+reg.

constexpr int N = 100000;
constexpr int E = 1200000;
constexpr int D = 64;    // input dim
constexpr int H = 128;   // hidden
constexpr int C = 40;    // classes
constexpr int NBUCK2 = 98;                      // buckets of 1024 dst nodes
constexpr int EBLK   = 2048;                    // edges per histo/append block
constexpr int NHB    = (E + EBLK - 1) / EBLK;   // 586 edge blocks

typedef _Float16 f16x8 __attribute__((ext_vector_type(8)));
typedef float    f32x4 __attribute__((ext_vector_type(4)));

// ---- W1 -> fragment-ordered fp16: wfrag[(ct*2+f)*64 + l][r] =
//      W1[f*32 + (l>>4)*8 + r][ct*16 + (l&15)]  (1024 entries x 16 B) ----
__global__ __launch_bounds__(256) void prep_w1(const float* __restrict__ W1,
                                               f16x8* __restrict__ wfrag) {
    int e = blockIdx.x * 256 + threadIdx.x;   // 4 blocks x 256 = 1024
    int l = e & 63, cf = e >> 6;              // cf = ct*2+f
    int f = cf & 1, ct = cf >> 1;
    int kbase = f * 32 + (l >> 4) * 8;
    int c = ct * 16 + (l & 15);
    f16x8 v;
#pragma unroll
    for (int r = 0; r < 8; ++r)
        v[r] = (_Float16)W1[(kbase + r) * H + c];
    wfrag[e] = v;
}

// ---- histo (98 buckets) + grid-stride h->fp16 convert prologue ----
__global__ __launch_bounds__(256) void histo_conv(const int2* __restrict__ edges,
                                                  int* __restrict__ partial,
                                                  const float2* __restrict__ hf,
                                                  __half2* __restrict__ HH) {
    __shared__ int cnt[NBUCK2];
    if (threadIdx.x < NBUCK2) cnt[threadIdx.x] = 0;
    for (int i = blockIdx.x * 256 + threadIdx.x; i < N * 32; i += NHB * 256) {
        float2 p = hf[i];
        HH[i] = __floats2half2_rn(p.x, p.y);
    }
    __syncthreads();
    int base = blockIdx.x * EBLK + threadIdx.x * 8;
#pragma unroll
    for (int i = 0; i < 8; ++i) {
        int e = base + i;
        if (e < E) atomicAdd(&cnt[edges[e].y >> 10], 1);
    }
    __syncthreads();
    if (threadIdx.x < NBUCK2)
        partial[blockIdx.x * NBUCK2 + threadIdx.x] = cnt[threadIdx.x];
}

// ---- per-bucket column scan of partial: obase[b][blk], btot[b] ----
__global__ __launch_bounds__(1024) void scan_pb(const int* __restrict__ partial,
                                                int* __restrict__ obase,
                                                int* __restrict__ btot) {
    __shared__ int s[1024];
    int b = blockIdx.x, t = threadIdx.x;
    int v = (t < NHB) ? partial[t * NBUCK2 + b] : 0;
    s[t] = v;
    __syncthreads();
    for (int off = 1; off < 1024; off <<= 1) {
        int x = (t >= off) ? s[t - off] : 0;
        __syncthreads();
        s[t] += x;
        __syncthreads();
    }
    if (t < NHB) obase[b * NHB + t] = s[t] - v;   // exclusive within bucket
    if (t == 1023) btot[b] = s[1023];
}

// ---- exclusive scan of bucket totals -> bstart[0..NBUCK2] ----
__global__ __launch_bounds__(128) void scan_bt(const int* __restrict__ btot,
                                               int* __restrict__ bstart) {
    __shared__ int s[128];
    int t = threadIdx.x;
    int v = (t < NBUCK2) ? btot[t] : 0;
    s[t] = v;
    __syncthreads();
    for (int off = 1; off < 128; off <<= 1) {
        int x = (t >= off) ? s[t - off] : 0;
        __syncthreads();
        s[t] += x;
        __syncthreads();
    }
    if (t < NBUCK2) bstart[t] = s[t] - v;
    if (t == NBUCK2 - 1) bstart[NBUCK2] = s[t];   // = E
}

// ---- append: deterministic positions, LDS cursors seeded from scanned bases ----
__global__ __launch_bounds__(256) void append_b(const int2* __restrict__ edges,
                                                const int* __restrict__ bstart,
                                                const int* __restrict__ obase,
                                                int* __restrict__ staging) {
    __shared__ int cur[NBUCK2];
    int blk = blockIdx.x;
    if (threadIdx.x < NBUCK2)
        cur[threadIdx.x] = bstart[threadIdx.x] + obase[threadIdx.x * NHB + blk];
    __syncthreads();
    int base = blk * EBLK + threadIdx.x * 8;
#pragma unroll
    for (int i = 0; i < 8; ++i) {
        int e = base + i;
        if (e < E) {
            int2 ed = edges[e];
            int b = ed.y >> 10;
            int p = atomicAdd(&cur[b], 1);               // LDS atomic
            staging[p] = (ed.x << 10) | (ed.y & 1023);   // src:17b | dst_local:10b
        }
    }
}

// ---- per-bucket: LDS count + scan -> rd(row_start,deg), scatter csr in window ----
__global__ __launch_bounds__(1024) void fill_b(const int* __restrict__ staging,
                                               const int* __restrict__ bstart,
                                               int2* __restrict__ rd,
                                               int* __restrict__ csr) {
    __shared__ int cnt[1024], s[1024], cur[1024];
    int b = blockIdx.x, t = threadIdx.x;
    cnt[t] = 0;
    __syncthreads();
    int lo = bstart[b], hi = bstart[b + 1];
    for (int i = lo + t; i < hi; i += 1024)
        atomicAdd(&cnt[staging[i] & 1023], 1);
    __syncthreads();
    int v = cnt[t];
    s[t] = v;
    __syncthreads();
    for (int off = 1; off < 1024; off <<= 1) {
        int x = (t >= off) ? s[t - off] : 0;
        __syncthreads();
        s[t] += x;
        __syncthreads();
    }
    int ex = s[t] - v;
    cur[t] = ex;
    int node = (b << 10) + t;
    if (node < N) rd[node] = make_int2(lo + ex, v);
    __syncthreads();
    for (int i = lo + t; i < hi; i += 1024) {
        int w = staging[i];
        int p = atomicAdd(&cur[w & 1023], 1);
        csr[lo + p] = w >> 10;
    }
}

// ---- FUSED layer 1: gather (4 nodes/wave, 16 lanes/node, batch-8) -> fp16 LDS
//      a_h[16][72], then XH = fp16(relu(a_h @ W1 + b1)) via 4x MFMA 16x16x32_f16
//      per wave (wave wv covers output cols wv*32..wv*32+31). LDS = 2.3 KB. ----
__global__ __launch_bounds__(256) void fused1(const __half2* __restrict__ HH,
                                              const int* __restrict__ csr,
                                              const int2* __restrict__ rd,
                                              const f16x8* __restrict__ wfrag,
                                              const float* __restrict__ b1,
                                              __half* __restrict__ XH) {
    __shared__ _Float16 a_h[16 * 72] __attribute__((aligned(16)));
    // ---- gather phase ----
    int node = blockIdx.x * 16 + (threadIdx.x >> 4);
    int nl = threadIdx.x >> 4;                 // node-local 0..15
    int fl = threadIdx.x & 15;
    const float2* H4 = (const float2*)HH;      // row = 16 float2 = 128 B
    int2 rdv = rd[node];
    int rs = rdv.x, d = rdv.y;
    if (d == 0) rs = 0;                        // safe dummy window
    int cl = (d > 0) ? d - 1 : 0;
    int dmax = d;                              // wave-uniform loop bound
    dmax = max(dmax, __shfl_xor(dmax, 16));
    dmax = max(dmax, __shfl_xor(dmax, 32));
    float a0, a1, a2, a3;
    {   // self-loop init
        float2 raw = H4[node * 16 + fl];
        const __half2* hp = (const __half2*)&raw;
        float2 v0 = __half22float2(hp[0]), v1 = __half22float2(hp[1]);
        a0 = v0.x; a1 = v0.y; a2 = v1.x; a3 = v1.y;
    }
    for (int j0 = 0; j0 < dmax; j0 += 8) {     // 8 rows in flight per node
        int k[8]; float w[8];
#pragma unroll
        for (int t = 0; t < 8; ++t) {
            int jj = j0 + t;
            bool ok = jj < d;
            w[t] = ok ? 1.f : 0.f;
            k[t] = csr[rs + (ok ? jj : cl)];
        }
#pragma unroll
        for (int t = 0; t < 8; ++t) {
            float2 raw = H4[k[t] * 16 + fl];
            const __half2* hp = (const __half2*)&raw;
            float2 v0 = __half22float2(hp[0]), v1 = __half22float2(hp[1]);
            a0 = fmaf(w[t], v0.x, a0); a1 = fmaf(w[t], v0.y, a1);
            a2 = fmaf(w[t], v1.x, a2); a3 = fmaf(w[t], v1.y, a3);
        }
    }
    *(__half2*)&a_h[nl * 72 + fl * 4]     = __floats2half2_rn(a0, a1);
    *(__half2*)&a_h[nl * 72 + fl * 4 + 2] = __floats2half2_rn(a2, a3);
    __syncthreads();
    // ---- MFMA phase: wave wv -> col tiles t0=2wv, t1=2wv+1 ----
    int wv = threadIdx.x >> 6;
    int l  = threadIdx.x & 63;
    int lg = l >> 4, lr = l & 15;
    f16x8 aA0 = *(const f16x8*)&a_h[lr * 72 + 0 * 32 + lg * 8];
    f16x8 aA1 = *(const f16x8*)&a_h[lr * 72 + 1 * 32 + lg * 8];
    int t0 = wv * 2, t1 = wv * 2 + 1;
    f16x8 b00 = wfrag[(t0 * 2 + 0) * 64 + l];
    f16x8 b01 = wfrag[(t0 * 2 + 1) * 64 + l];
    f16x8 b10 = wfrag[(t1 * 2 + 0) * 64 + l];
    f16x8 b11 = wfrag[(t1 * 2 + 1) * 64 + l];
    f32x4 acc0 = {0.f, 0.f, 0.f, 0.f}, acc1 = {0.f, 0.f, 0.f, 0.f};
    acc0 = __builtin_amdgcn_mfma_f32_16x16x32_f16(aA0, b00, acc0, 0, 0, 0);
    acc0 = __builtin_amdgcn_mfma_f32_16x16x32_f16(aA1, b01, acc0, 0, 0, 0);
    acc1 = __builtin_amdgcn_mfma_f32_16x16x32_f16(aA0, b10, acc1, 0, 0, 0);
    acc1 = __builtin_amdgcn_mfma_f32_16x16x32_f16(aA1, b11, acc1, 0, 0, 0);
    // ---- epilogue: D col = lane&15, row = (lane>>4)*4 + r (verified layout) ----
    int row0 = blockIdx.x * 16;
    int c0 = t0 * 16 + lr, c1 = t1 * 16 + lr;
    float bias0 = b1[c0], bias1 = b1[c1];
#pragma unroll
    for (int r = 0; r < 4; ++r) {
        int row = row0 + lg * 4 + r;
        XH[row * H + c0] = __float2half_rn(fmaxf(acc0[r] + bias0, 0.f));
        XH[row * H + c1] = __float2half_rn(fmaxf(acc1[r] + bias1, 0.f));
    }
}

// ---- ZH = fp16(XH @ W2), row stride 64 halves, cols 40..63 zero-filled ----
constexpr int XS = 132;
__global__ __launch_bounds__(256) void gemm2(const __half* __restrict__ XH,
                                             const float* __restrict__ W2,
                                             __half* __restrict__ ZH) {
    __shared__ float w_s[H * C];        // 20 KB
    __shared__ float x_s[64 * XS];      // 33.8 KB
    int row0 = blockIdx.x * 64;
    {
        const float4* src = (const float4*)W2;
        float4* dst = (float4*)w_s;
#pragma unroll
        for (int i = 0; i < 5; ++i)
            dst[threadIdx.x + i * 256] = src[threadIdx.x + i * 256];
    }
    {   // stage XH (fp16) -> x_s (fp32): 64 rows x 16 chunks of 8 halves
#pragma unroll
        for (int i = 0; i < 4; ++i) {
            int idx = threadIdx.x + i * 256;   // 1024 chunks
            int r = idx >> 4;
            int q = idx & 15;
            int grow = row0 + r;
            if (grow >= N) grow = N - 1;
            float4 raw = *(const float4*)&XH[grow * H + q * 8];
            __half2* hp = (__half2*)&raw;
            float2 f0 = __half22float2(hp[0]), f1 = __half22float2(hp[1]);
            float2 f2 = __half22float2(hp[2]), f3 = __half22float2(hp[3]);
            float* dst = &x_s[r * XS + q * 8];
            dst[0] = f0.x; dst[1] = f0.y; dst[2] = f1.x; dst[3] = f1.y;
            dst[4] = f2.x; dst[5] = f2.y; dst[6] = f3.x; dst[7] = f3.y;
        }
    }
    __syncthreads();

    int tc   = threadIdx.x & 7;         // cols tc*5 .. tc*5+4
    int trow = threadIdx.x >> 3;        // rows trow*2, trow*2+1
    float acc[2][5] = {};
#pragma unroll 4
    for (int k = 0; k < H; ++k) {
        float b[5];
#pragma unroll
        for (int j = 0; j < 5; ++j) b[j] = w_s[k * C + tc * 5 + j];
        float a0 = x_s[(trow * 2) * XS + k];
        float a1 = x_s[(trow * 2 + 1) * XS + k];
#pragma unroll
        for (int j = 0; j < 5; ++j) {
            acc[0][j] = fmaf(a0, b[j], acc[0][j]);
            acc[1][j] = fmaf(a1, b[j], acc[1][j]);
        }
    }
#pragma unroll
    for (int i = 0; i < 2; ++i) {
        int row = row0 + trow * 2 + i;
        if (row < N) {
#pragma unroll
            for (int j = 0; j < 5; ++j)
                ZH[row * 64 + tc * 5 + j] = __float2half_rn(acc[i][j]);
#pragma unroll
            for (int j = 0; j < 3; ++j)          // pad cols 40..63
                ZH[row * 64 + 40 + tc * 3 + j] = __half(0.f);
        }
    }
}

// ---- out[node] = softmax(Z[node] + sum Z[src] + b2): 4 nodes/wave, 16 lanes/node.
//      Lanes fl>=10 carry the zero-pad cols; -inf mask makes exp->0 so only the
//      max needs masking. 16-lane xor reduces; float4 store for fl<10. ----
__global__ __launch_bounds__(256) void gather2_softmax(const __half2* __restrict__ ZH,
                                                       const int* __restrict__ csr,
                                                       const int2* __restrict__ rd,
                                                       const float* __restrict__ b2,
                                                       float4* __restrict__ out) {
    int node = blockIdx.x * 16 + (threadIdx.x >> 4);
    int fl = threadIdx.x & 15;
    const float2* Z4 = (const float2*)ZH;     // row = 16 float2 = 128 B (padded)
    int2 rdv = rd[node];
    int rs = rdv.x, d = rdv.y;
    if (d == 0) rs = 0;
    int cl = (d > 0) ? d - 1 : 0;
    int dmax = d;
    dmax = max(dmax, __shfl_xor(dmax, 16));
    dmax = max(dmax, __shfl_xor(dmax, 32));
    float a0, a1, a2, a3;
    {   // self-loop init
        float2 raw = Z4[node * 16 + fl];
        const __half2* hp = (const __half2*)&raw;
        float2 v0 = __half22float2(hp[0]), v1 = __half22float2(hp[1]);
        a0 = v0.x; a1 = v0.y; a2 = v1.x; a3 = v1.y;
    }
    for (int j0 = 0; j0 < dmax; j0 += 8) {
        int k[8]; float w[8];
#pragma unroll
        for (int t = 0; t < 8; ++t) {
            int jj = j0 + t;
            bool ok = jj < d;
            w[t] = ok ? 1.f : 0.f;
            k[t] = csr[rs + (ok ? jj : cl)];
        }
#pragma unroll
        for (int t = 0; t < 8; ++t) {
            float2 raw = Z4[k[t] * 16 + fl];
            const __half2* hp = (const __half2*)&raw;
            float2 v0 = __half22float2(hp[0]), v1 = __half22float2(hp[1]);
            a0 = fmaf(w[t], v0.x, a0); a1 = fmaf(w[t], v0.y, a1);
            a2 = fmaf(w[t], v1.x, a2); a3 = fmaf(w[t], v1.y, a3);
        }
    }
    // softmax over the 40 real cols (lanes fl<10, cols 4fl..4fl+3)
    const float4* b4 = (const float4*)b2;
    bool real = fl < 10;
    float4 bb = b4[real ? fl : 9];
    float v0 = real ? a0 + bb.x : -INFINITY;
    float v1 = real ? a1 + bb.y : -INFINITY;
    float v2 = real ? a2 + bb.z : -INFINITY;
    float v3 = real ? a3 + bb.w : -INFINITY;
    float m = fmaxf(fmaxf(v0, v1), fmaxf(v2, v3));
#pragma unroll
    for (int off = 1; off < 16; off <<= 1) m = fmaxf(m, __shfl_xor(m, off));
    float e0 = __expf(v0 - m), e1 = __expf(v1 - m);   // -inf lanes -> exp = 0
    float e2 = __expf(v2 - m), e3 = __expf(v3 - m);
    float s = (e0 + e1) + (e2 + e3);
#pragma unroll
    for (int off = 1; off < 16; off <<= 1) s += __shfl_xor(s, off);
    float inv = 1.f / s;
    if (real)
        out[node * 10 + fl] = make_float4(e0 * inv, e1 * inv, e2 * inv, e3 * inv);
}

extern "C" void kernel_launch(void* const* d_in, const int* in_sizes, int n_in,
                              void* d_out, int out_size, void* d_ws, size_t ws_size,
                              hipStream_t stream) {
    const float* h   = (const float*)d_in[0];   // N*D
    const int*   adj = (const int*)  d_in[1];   // E*2
    const float* W1  = (const float*)d_in[2];   // D*H
    const float* b1  = (const float*)d_in[3];   // H
    const float* W2  = (const float*)d_in[4];   // H*C
    const float* b2  = (const float*)d_in[5];   // C
    float* out = (float*)d_out;                 // N*C fp32

    // workspace, NO aliasing (w1frag lives in the dead agg1 slot):
    //   agg1-slot (w1frag 16 KB) | HH fp16 N*64 | XH fp16 N*128 | ZH fp16 N*64 | ints
    float*  agg1 = (float*)d_ws;                        // N*64 fp32 slot
    f16x8*  w1frag = (f16x8*)agg1;                      // 1024 x 16 B
    __half* HH   = (__half*)(agg1 + (size_t)N * 64);    // N*64 fp16
    __half* XH   = HH + (size_t)N * 64;                 // N*128 fp16
    __half* ZH   = XH + (size_t)N * H;                  // N*64 fp16
    int* partial   = (int*)(ZH + (size_t)N * 64);       // NHB*NBUCK2
    int* obase     = partial + NHB * NBUCK2;            // NBUCK2*NHB
    int* btot      = obase + NBUCK2 * NHB;              // 128
    int* bstart    = btot + 128;                        // NBUCK2+1 (pad 128)
    int* staging   = bstart + 128;                      // E
    int* csr       = staging + E;                       // E
    int2* rd       = (int2*)(csr + E);                  // N (row_start, deg)

    prep_w1   <<<4, 256, 0, stream>>>(W1, w1frag);
    histo_conv<<<NHB, 256, 0, stream>>>((const int2*)adj, partial,
                                        (const float2*)h, (__half2*)HH);
    scan_pb   <<<NBUCK2, 1024, 0, stream>>>(partial, obase, btot);
    scan_bt   <<<1, 128, 0, stream>>>(btot, bstart);
    append_b  <<<NHB, 256, 0, stream>>>((const int2*)adj, bstart, obase, staging);
    fill_b    <<<NBUCK2, 1024, 0, stream>>>(staging, bstart, rd, csr);

    fused1         <<<N / 16, 256, 0, stream>>>((const __half2*)HH, csr, rd,
                                                w1frag, b1, XH);
    gemm2          <<<(N + 63) / 64, 256, 0, stream>>>(XH, W2, ZH);
    gather2_softmax<<<N / 16, 256, 0, stream>>>((const __half2*)ZH, csr, rd,
                                                b2, (float4*)out);
}